// Round 1
// baseline (610.185 us; speedup 1.0000x reference)
//
#include <hip/hip_runtime.h>

// BjorckLinear: out = X @ bjorck10(W)^T
//   X: [131072, 512] f32, W: [512, 512] f32, out: [131072, 512] f32
// Bjorck: 10x  W <- 1.5 W - 0.5 W (W^T W)   (early-stop provably never fires)
//
// Precision: Bjorck matmuls use split-bf16 (hi + lo) with 3 MFMA terms
// (hi*hi + hi*lo + lo*hi) => ~2^-17 relative per matmul, safe against the
// x1.5/iter small-singular-value error amplification. Final GEMM is plain
// bf16 (error ~0.01 absmax vs 0.11 threshold).

using bf16x8 = __attribute__((ext_vector_type(8))) short;
using f32x4  = __attribute__((ext_vector_type(4))) float;
using u16x8  = __attribute__((ext_vector_type(8))) unsigned short;

#define DI 512

__device__ __forceinline__ unsigned short f2bf(float f) {
  unsigned int u = __builtin_bit_cast(unsigned int, f);
  u += 0x7FFFu + ((u >> 16) & 1u);   // round-to-nearest-even
  return (unsigned short)(u >> 16);
}
__device__ __forceinline__ float bf2f(unsigned short h) {
  unsigned int u = ((unsigned int)h) << 16;
  return __builtin_bit_cast(float, u);
}

// ---- initial split: W f32 -> f32 master copy + hi/lo bf16 (+ transposed) ----
__global__ void k_split(const float* __restrict__ W, float* __restrict__ Wm,
                        unsigned short* __restrict__ Wh, unsigned short* __restrict__ Wl,
                        unsigned short* __restrict__ WTh, unsigned short* __restrict__ WTl) {
  int idx = blockIdx.x * blockDim.x + threadIdx.x;   // 0..262143
  int m = idx >> 9, i = idx & 511;
  float w = W[idx];
  Wm[idx] = w;
  unsigned short h  = f2bf(w);
  unsigned short lo = f2bf(w - bf2f(h));
  Wh[idx] = h; Wl[idx] = lo;
  WTh[i * DI + m] = h; WTl[i * DI + m] = lo;   // transposed copies for the gram step
}

// ---- generic 512x512 NT GEMM, 3 split-bf16 terms, two epilogues ----
// C[m][n] = sum_k A'[m][k] * B'[n][k]   (A' = Ah+Al, B' = Bh+Bl; l*l term dropped)
// mode 0 (gram):   write C as hi/lo bf16 -> Oh, Ol
// mode 1 (update): Wnew = 1.5*Wm_in - 0.5*C; write f32 master + hi/lo + transposed hi/lo
__global__ __launch_bounds__(256) void k_mm(
    const unsigned short* __restrict__ Ah, const unsigned short* __restrict__ Al,
    const unsigned short* __restrict__ Bh, const unsigned short* __restrict__ Bl,
    int mode,
    const float* __restrict__ Wm_in, float* __restrict__ Wm_out,
    unsigned short* __restrict__ Oh, unsigned short* __restrict__ Ol,
    unsigned short* __restrict__ OTh, unsigned short* __restrict__ OTl) {
  __shared__ unsigned short sA[64][72];   // +8 pad: 144B row stride -> ~2-way banks (free)
  __shared__ unsigned short sB[64][72];
  const int tid = threadIdx.x;
  const int bx  = blockIdx.x;            // 64 blocks: 8x8 tiles of 64x64
  const int tm  = (bx >> 3) << 6;
  const int tn  = (bx & 7) << 6;
  const int w   = tid >> 6, l = tid & 63;

  f32x4 acc[4] = {};

  const unsigned short* As[3] = {Ah, Ah, Al};
  const unsigned short* Bs[3] = {Bh, Bl, Bh};

  const int srow = tid >> 3;              // 0..31 (two passes cover 64 rows)
  const int schunk = (tid & 7) << 3;      // 8-elem (16B) chunk

#pragma unroll
  for (int term = 0; term < 3; ++term) {
    const unsigned short* A = As[term];
    const unsigned short* B = Bs[term];
    for (int k0 = 0; k0 < DI; k0 += 64) {
      __syncthreads();
      *(u16x8*)&sA[srow][schunk]      = *(const u16x8*)&A[(tm + srow) * DI + k0 + schunk];
      *(u16x8*)&sA[srow + 32][schunk] = *(const u16x8*)&A[(tm + srow + 32) * DI + k0 + schunk];
      *(u16x8*)&sB[srow][schunk]      = *(const u16x8*)&B[(tn + srow) * DI + k0 + schunk];
      *(u16x8*)&sB[srow + 32][schunk] = *(const u16x8*)&B[(tn + srow + 32) * DI + k0 + schunk];
      __syncthreads();
#pragma unroll
      for (int kc = 0; kc < 2; ++kc) {
        const int ke = kc * 32 + ((l >> 4) << 3);
        bf16x8 a = *(const bf16x8*)&sA[(w << 4) + (l & 15)][ke];
#pragma unroll
        for (int c = 0; c < 4; ++c) {
          bf16x8 b = *(const bf16x8*)&sB[(c << 4) + (l & 15)][ke];
          acc[c] = __builtin_amdgcn_mfma_f32_16x16x32_bf16(a, b, acc[c], 0, 0, 0);
        }
      }
    }
  }

  // epilogue: D[row=(l>>4)*4+r][col=l&15] per verified gfx950 C/D mapping
  const int r0 = tm + (w << 4) + ((l >> 4) << 2);
  const int cn = l & 15;
#pragma unroll
  for (int c = 0; c < 4; ++c) {
#pragma unroll
    for (int r = 0; r < 4; ++r) {
      const int gm = r0 + r;
      const int gn = tn + (c << 4) + cn;
      const float v = acc[c][r];
      if (mode == 0) {
        unsigned short h = f2bf(v);
        Oh[gm * DI + gn] = h;
        Ol[gm * DI + gn] = f2bf(v - bf2f(h));
      } else {
        const float wn = 1.5f * Wm_in[gm * DI + gn] - 0.5f * v;
        Wm_out[gm * DI + gn] = wn;
        unsigned short h  = f2bf(wn);
        unsigned short lo = f2bf(wn - bf2f(h));
        Oh[gm * DI + gn] = h;   Ol[gm * DI + gn] = lo;
        OTh[gn * DI + gm] = h;  OTl[gn * DI + gm] = lo;
      }
    }
  }
}

// ---- big GEMM: out[131072][512] = bf16(X) @ Wp^T ----
// BM=64 rows/block, full N=512 (X read exactly once), BK=32, 4 waves.
__global__ __launch_bounds__(256, 2) void k_big(
    const float* __restrict__ X, const unsigned short* __restrict__ Wp,
    float* __restrict__ out) {
  __shared__ unsigned short sX[64][40];    // +8 pad: 80B stride -> 2-way banks
  __shared__ unsigned short sW[512][40];
  const int tid = threadIdx.x;
  const int w = tid >> 6, l = tid & 63;

  f32x4 acc[32] = {};

  const int xrow = tid >> 2, xoff = (tid & 3) << 3;   // 64 rows x 32 f32
  const int wrow = tid >> 2, wchunk = (tid & 3) << 3; // 512 rows x 32 bf16 (8 passes)
  const int rowbase = blockIdx.x << 6;

  for (int k0 = 0; k0 < 512; k0 += 32) {
    __syncthreads();
    {
      const float* xp = &X[(rowbase + xrow) * 512 + k0 + xoff];
      f32x4 v0 = *(const f32x4*)xp;
      f32x4 v1 = *(const f32x4*)(xp + 4);
      u16x8 h;
      h[0] = f2bf(v0[0]); h[1] = f2bf(v0[1]); h[2] = f2bf(v0[2]); h[3] = f2bf(v0[3]);
      h[4] = f2bf(v1[0]); h[5] = f2bf(v1[1]); h[6] = f2bf(v1[2]); h[7] = f2bf(v1[3]);
      *(u16x8*)&sX[xrow][xoff] = h;
    }
#pragma unroll
    for (int p = 0; p < 8; ++p) {
      *(u16x8*)&sW[wrow + p * 64][wchunk] =
          *(const u16x8*)&Wp[(wrow + p * 64) * 512 + k0 + wchunk];
    }
    __syncthreads();
    const int ke = (l >> 4) << 3;
    bf16x8 a = *(const bf16x8*)&sX[(w << 4) + (l & 15)][ke];
#pragma unroll
    for (int c = 0; c < 32; ++c) {
      bf16x8 b = *(const bf16x8*)&sW[(c << 4) + (l & 15)][ke];
      acc[c] = __builtin_amdgcn_mfma_f32_16x16x32_bf16(a, b, acc[c], 0, 0, 0);
    }
  }

  const int r0 = rowbase + (w << 4) + ((l >> 4) << 2);
  const int cn = l & 15;
#pragma unroll
  for (int c = 0; c < 32; ++c) {
#pragma unroll
    for (int r = 0; r < 4; ++r) {
      out[(r0 + r) * 512 + (c << 4) + cn] = acc[c][r];
    }
  }
}

extern "C" void kernel_launch(void* const* d_in, const int* in_sizes, int n_in,
                              void* d_out, int out_size, void* d_ws, size_t ws_size,
                              hipStream_t stream) {
  const float* X = (const float*)d_in[0];   // inputs [131072,512]
  const float* W = (const float*)d_in[1];   // weight [512,512]
  float* out = (float*)d_out;

  char* ws = (char*)d_ws;
  size_t off = 0;
  auto carve = [&](size_t bytes) { void* p = ws + off; off += (bytes + 255) & ~(size_t)255; return p; };

  const size_t F32 = (size_t)DI * DI * 4;   // 1 MB
  const size_t BF  = (size_t)DI * DI * 2;   // 0.5 MB

  float* Wm[2];           unsigned short *Wh[2], *Wl[2], *WTh[2], *WTl[2];
  Wm[0]  = (float*)carve(F32);          Wm[1]  = (float*)carve(F32);
  Wh[0]  = (unsigned short*)carve(BF);  Wh[1]  = (unsigned short*)carve(BF);
  Wl[0]  = (unsigned short*)carve(BF);  Wl[1]  = (unsigned short*)carve(BF);
  WTh[0] = (unsigned short*)carve(BF);  WTh[1] = (unsigned short*)carve(BF);
  WTl[0] = (unsigned short*)carve(BF);  WTl[1] = (unsigned short*)carve(BF);
  unsigned short* Gh = (unsigned short*)carve(BF);
  unsigned short* Gl = (unsigned short*)carve(BF);

  // phase 0: split input weight
  k_split<<<1024, 256, 0, stream>>>(W, Wm[0], Wh[0], Wl[0], WTh[0], WTl[0]);

  // phase 1: 10 Bjorck iterations (gram + update), ping-pong W buffers
  int cur = 0;
  for (int it = 0; it < 10; ++it) {
    // G = W'^T W'  (NT gemm on transposed-W arrays), split to bf16 hi/lo
    k_mm<<<64, 256, 0, stream>>>(WTh[cur], WTl[cur], WTh[cur], WTl[cur], 0,
                                 nullptr, nullptr, Gh, Gl, nullptr, nullptr);
    const int nxt = cur ^ 1;
    // Wnew = 1.5 W - 0.5 W' G'   (B = G rows; G is symmetric)
    k_mm<<<64, 256, 0, stream>>>(Wh[cur], Wl[cur], Gh, Gl, 1,
                                 Wm[cur], Wm[nxt], Wh[nxt], Wl[nxt], WTh[nxt], WTl[nxt]);
    cur = nxt;
  }

  // phase 2: out = bf16(X) @ Wp^T
  k_big<<<2048, 256, 0, stream>>>(X, Wh[cur], out);
}

// Round 2
// 369.838 us; speedup vs baseline: 1.6499x; 1.6499x over previous
//
#include <hip/hip_runtime.h>

// BjorckLinear: out = X @ bjorck10(W)^T
//   X: [131072, 512] f32, W: [512, 512] f32, out: [131072, 512] f32
// Bjorck: 10x  W <- 1.5 W - 0.5 W (W^T W)   (early-stop provably never fires)
//
// R2: (a) k_mm -> wave-per-16x16-tile, no LDS/barriers (L2-resident operands);
//     (b) k_big waves repartitioned by n: 12 ds_reads per 32 MFMAs (was 33).

using bf16x8 = __attribute__((ext_vector_type(8))) short;
using f32x4  = __attribute__((ext_vector_type(4))) float;
using u16x8  = __attribute__((ext_vector_type(8))) unsigned short;

#define DI 512

__device__ __forceinline__ unsigned short f2bf(float f) {
  unsigned int u = __builtin_bit_cast(unsigned int, f);
  u += 0x7FFFu + ((u >> 16) & 1u);   // round-to-nearest-even
  return (unsigned short)(u >> 16);
}
__device__ __forceinline__ float bf2f(unsigned short h) {
  unsigned int u = ((unsigned int)h) << 16;
  return __builtin_bit_cast(float, u);
}

// ---- initial split: W f32 -> f32 master copy + hi/lo bf16 (+ transposed) ----
__global__ void k_split(const float* __restrict__ W, float* __restrict__ Wm,
                        unsigned short* __restrict__ Wh, unsigned short* __restrict__ Wl,
                        unsigned short* __restrict__ WTh, unsigned short* __restrict__ WTl) {
  int idx = blockIdx.x * blockDim.x + threadIdx.x;   // 0..262143
  int m = idx >> 9, i = idx & 511;
  float w = W[idx];
  Wm[idx] = w;
  unsigned short h  = f2bf(w);
  unsigned short lo = f2bf(w - bf2f(h));
  Wh[idx] = h; Wl[idx] = lo;
  WTh[i * DI + m] = h; WTl[i * DI + m] = lo;
}

// ---- 512x512 NT GEMM: one wave per 16x16 tile, no LDS, no __syncthreads ----
// C[m][n] = sum_k A'[m][k] * B'[n][k]  (A'=Ah+Al, B'=Bh+Bl; l*l term dropped)
// mode 0 (gram):   write C as hi/lo bf16 -> Oh, Ol
// mode 1 (update): Wnew = 1.5*Wm_in - 0.5*C; write f32 + hi/lo + transposed hi/lo
__global__ __launch_bounds__(256) void k_mm2(
    const unsigned short* __restrict__ Ah, const unsigned short* __restrict__ Al,
    const unsigned short* __restrict__ Bh, const unsigned short* __restrict__ Bl,
    int mode,
    const float* __restrict__ Wm_in, float* __restrict__ Wm_out,
    unsigned short* __restrict__ Oh, unsigned short* __restrict__ Ol,
    unsigned short* __restrict__ OTh, unsigned short* __restrict__ OTl) {
  const int tid = threadIdx.x;
  const int l   = tid & 63;
  const int wid = (blockIdx.x << 2) | (tid >> 6);   // 0..1023 -> 32x32 tiles
  const int m0  = (wid >> 5) << 4;
  const int n0  = (wid & 31) << 4;

  const int ra = (m0 + (l & 15)) * DI + ((l >> 4) << 3);
  const int rb = (n0 + (l & 15)) * DI + ((l >> 4) << 3);

  // 6 independent accumulator chains (3 terms x 2 k-parities) for MFMA ILP
  f32x4 a0 = {}, a1 = {}, a2 = {}, a3 = {}, a4 = {}, a5 = {};
#pragma unroll
  for (int k0 = 0; k0 < DI; k0 += 64) {
    bf16x8 ah0 = *(const bf16x8*)&Ah[ra + k0];
    bf16x8 al0 = *(const bf16x8*)&Al[ra + k0];
    bf16x8 bh0 = *(const bf16x8*)&Bh[rb + k0];
    bf16x8 bl0 = *(const bf16x8*)&Bl[rb + k0];
    bf16x8 ah1 = *(const bf16x8*)&Ah[ra + k0 + 32];
    bf16x8 al1 = *(const bf16x8*)&Al[ra + k0 + 32];
    bf16x8 bh1 = *(const bf16x8*)&Bh[rb + k0 + 32];
    bf16x8 bl1 = *(const bf16x8*)&Bl[rb + k0 + 32];
    a0 = __builtin_amdgcn_mfma_f32_16x16x32_bf16(ah0, bh0, a0, 0, 0, 0);
    a1 = __builtin_amdgcn_mfma_f32_16x16x32_bf16(ah0, bl0, a1, 0, 0, 0);
    a2 = __builtin_amdgcn_mfma_f32_16x16x32_bf16(al0, bh0, a2, 0, 0, 0);
    a3 = __builtin_amdgcn_mfma_f32_16x16x32_bf16(ah1, bh1, a3, 0, 0, 0);
    a4 = __builtin_amdgcn_mfma_f32_16x16x32_bf16(ah1, bl1, a4, 0, 0, 0);
    a5 = __builtin_amdgcn_mfma_f32_16x16x32_bf16(al1, bh1, a5, 0, 0, 0);
  }
  f32x4 acc = (a0 + a1) + (a2 + a3) + (a4 + a5);

  const int r0 = m0 + ((l >> 4) << 2);
  const int cn = n0 + (l & 15);
#pragma unroll
  for (int r = 0; r < 4; ++r) {
    const int gm = r0 + r, gn = cn;
    const float v = acc[r];
    if (mode == 0) {
      unsigned short h = f2bf(v);
      Oh[gm * DI + gn] = h;
      Ol[gm * DI + gn] = f2bf(v - bf2f(h));
    } else {
      const float wn = 1.5f * Wm_in[gm * DI + gn] - 0.5f * v;
      Wm_out[gm * DI + gn] = wn;
      unsigned short h  = f2bf(wn);
      unsigned short lo = f2bf(wn - bf2f(h));
      Oh[gm * DI + gn] = h;   Ol[gm * DI + gn] = lo;
      OTh[gn * DI + gm] = h;  OTl[gn * DI + gm] = lo;
    }
  }
}

// ---- big GEMM: out[131072][512] = bf16(X) @ Wp^T ----
// BM=64, BN=512 (X read once), BK=32, 4 waves; wave w owns n in [w*128, w*128+128):
// per k-step per wave: 4 a-frags + 8 b-frags (12 ds_read_b128) -> 32 MFMAs.
__global__ __launch_bounds__(256, 2) void k_big(
    const float* __restrict__ X, const unsigned short* __restrict__ Wp,
    float* __restrict__ out) {
  __shared__ unsigned short sX[64][40];    // stride 20 dwords: uniform bank spread
  __shared__ unsigned short sW[512][40];
  const int tid = threadIdx.x;
  const int w = tid >> 6, l = tid & 63;

  f32x4 acc[4][8] = {};

  const int xrow = tid >> 2, xoff = (tid & 3) << 3;
  const int wrow = tid >> 2, wchunk = (tid & 3) << 3;
  const int rowbase = blockIdx.x << 6;

  for (int k0 = 0; k0 < 512; k0 += 32) {
    __syncthreads();
    {
      const float* xp = &X[(rowbase + xrow) * 512 + k0 + xoff];
      f32x4 v0 = *(const f32x4*)xp;
      f32x4 v1 = *(const f32x4*)(xp + 4);
      u16x8 h;
      h[0] = f2bf(v0[0]); h[1] = f2bf(v0[1]); h[2] = f2bf(v0[2]); h[3] = f2bf(v0[3]);
      h[4] = f2bf(v1[0]); h[5] = f2bf(v1[1]); h[6] = f2bf(v1[2]); h[7] = f2bf(v1[3]);
      *(u16x8*)&sX[xrow][xoff] = h;
    }
#pragma unroll
    for (int p = 0; p < 8; ++p) {
      *(u16x8*)&sW[wrow + p * 64][wchunk] =
          *(const u16x8*)&Wp[(wrow + p * 64) * 512 + k0 + wchunk];
    }
    __syncthreads();
    const int ke = (l >> 4) << 3;
    bf16x8 a[4], b[8];
#pragma unroll
    for (int mf = 0; mf < 4; ++mf)
      a[mf] = *(const bf16x8*)&sX[(mf << 4) + (l & 15)][ke];
#pragma unroll
    for (int nf = 0; nf < 8; ++nf)
      b[nf] = *(const bf16x8*)&sW[(w << 7) + (nf << 4) + (l & 15)][ke];
#pragma unroll
    for (int mf = 0; mf < 4; ++mf)
#pragma unroll
      for (int nf = 0; nf < 8; ++nf)
        acc[mf][nf] = __builtin_amdgcn_mfma_f32_16x16x32_bf16(a[mf], b[nf], acc[mf][nf], 0, 0, 0);
  }

  const int cn = l & 15;
#pragma unroll
  for (int mf = 0; mf < 4; ++mf) {
    const int r0 = rowbase + (mf << 4) + ((l >> 4) << 2);
#pragma unroll
    for (int nf = 0; nf < 8; ++nf) {
      const int col = (w << 7) + (nf << 4) + cn;
#pragma unroll
      for (int r = 0; r < 4; ++r)
        out[(r0 + r) * 512 + col] = acc[mf][nf][r];
    }
  }
}

extern "C" void kernel_launch(void* const* d_in, const int* in_sizes, int n_in,
                              void* d_out, int out_size, void* d_ws, size_t ws_size,
                              hipStream_t stream) {
  const float* X = (const float*)d_in[0];
  const float* W = (const float*)d_in[1];
  float* out = (float*)d_out;

  char* ws = (char*)d_ws;
  size_t off = 0;
  auto carve = [&](size_t bytes) { void* p = ws + off; off += (bytes + 255) & ~(size_t)255; return p; };

  const size_t F32 = (size_t)DI * DI * 4;
  const size_t BF  = (size_t)DI * DI * 2;

  float* Wm[2];           unsigned short *Wh[2], *Wl[2], *WTh[2], *WTl[2];
  Wm[0]  = (float*)carve(F32);          Wm[1]  = (float*)carve(F32);
  Wh[0]  = (unsigned short*)carve(BF);  Wh[1]  = (unsigned short*)carve(BF);
  Wl[0]  = (unsigned short*)carve(BF);  Wl[1]  = (unsigned short*)carve(BF);
  WTh[0] = (unsigned short*)carve(BF);  WTh[1] = (unsigned short*)carve(BF);
  WTl[0] = (unsigned short*)carve(BF);  WTl[1] = (unsigned short*)carve(BF);
  unsigned short* Gh = (unsigned short*)carve(BF);
  unsigned short* Gl = (unsigned short*)carve(BF);

  k_split<<<1024, 256, 0, stream>>>(W, Wm[0], Wh[0], Wl[0], WTh[0], WTl[0]);

  int cur = 0;
  for (int it = 0; it < 10; ++it) {
    // G = W^T W  (NT on transposed-W arrays)
    k_mm2<<<256, 256, 0, stream>>>(WTh[cur], WTl[cur], WTh[cur], WTl[cur], 0,
                                   nullptr, nullptr, Gh, Gl, nullptr, nullptr);
    const int nxt = cur ^ 1;
    // Wnew = 1.5 W - 0.5 W G   (G symmetric)
    k_mm2<<<256, 256, 0, stream>>>(Wh[cur], Wl[cur], Gh, Gl, 1,
                                   Wm[cur], Wm[nxt], Wh[nxt], Wl[nxt], WTh[nxt], WTl[nxt]);
    cur = nxt;
  }

  k_big<<<2048, 256, 0, stream>>>(X, Wh[cur], out);
}